// Round 1
// baseline (3519.695 us; speedup 1.0000x reference)
//
#include <hip/hip_runtime.h>
#include <hip/hip_bf16.h>
#include <cstdint>

#define NN 50000
#define EE 800000
#define RR 8
#define GG 128
#define D0 384
#define DL 256

__device__ __forceinline__ float sigmoidf_(float x) { return 1.0f / (1.0f + expf(-x)); }

// order-preserving float->uint encoding for atomicMax
__device__ __forceinline__ unsigned fenc(float x) {
    unsigned u = __float_as_uint(x);
    return (u & 0x80000000u) ? ~u : (u | 0x80000000u);
}
__device__ __forceinline__ float fdec(unsigned u) {
    unsigned b = (u & 0x80000000u) ? (u & 0x7fffffffu) : ~u;
    return __uint_as_float(b);
}

// ---------------- embedding concat: h0[n, 0:384] ----------------
__global__ __launch_bounds__(256) void embed_kernel(
    const int* __restrict__ x,
    const float* __restrict__ e0, const float* __restrict__ e1,
    const float* __restrict__ e2, const float* __restrict__ e3,
    const float* __restrict__ e4, const float* __restrict__ e5,
    float* __restrict__ h0)
{
    int idx = blockIdx.x * 256 + threadIdx.x;   // over NN*96 float4s
    if (idx >= NN * 96) return;
    int n = idx / 96;
    int q = idx - n * 96;
    int d = q * 4;
    int tbl = d >> 6;
    int w = d & 63;
    int row = x[n * 6 + tbl];
    const float* src;
    switch (tbl) {
        case 0: src = e0; break; case 1: src = e1; break; case 2: src = e2; break;
        case 3: src = e3; break; case 4: src = e4; break; default: src = e5; break;
    }
    *(float4*)&h0[(size_t)n * D0 + d] = *(const float4*)&src[row * 64 + w];
}

// ---------------- CSR build ----------------
__global__ __launch_bounds__(256) void count_kernel(
    const int* __restrict__ dst, const int* __restrict__ et, int* __restrict__ counts)
{
    int i = blockIdx.x * 256 + threadIdx.x;
    if (i < EE) atomicAdd(&counts[dst[i] * RR + et[i]], 1);
}

#define SCAN_CHUNK 4096
__global__ __launch_bounds__(256) void scanA_kernel(const int* __restrict__ cnt, int M, int* __restrict__ blkSums)
{
    __shared__ int s[256];
    int b = blockIdx.x, t = threadIdx.x;
    int base = b * SCAN_CHUNK + t * 16;
    int tot = 0;
    #pragma unroll
    for (int i = 0; i < 16; i++) { int idx = base + i; if (idx < M) tot += cnt[idx]; }
    s[t] = tot; __syncthreads();
    for (int off = 128; off > 0; off >>= 1) {
        if (t < off) s[t] += s[t + off];
        __syncthreads();
    }
    if (t == 0) blkSums[b] = s[0];
}

__global__ void scanB_kernel(const int* __restrict__ blkSums, int NB, int* __restrict__ blkOff)
{
    if (threadIdx.x == 0) {
        int run = 0;
        for (int i = 0; i < NB; i++) { blkOff[i] = run; run += blkSums[i]; }
    }
}

__global__ __launch_bounds__(256) void scanC_kernel(
    const int* __restrict__ cnt, int M, const int* __restrict__ blkOff,
    int* __restrict__ offs, int* __restrict__ curs)
{
    __shared__ int s[256];
    int b = blockIdx.x, t = threadIdx.x;
    int base = b * SCAN_CHUNK + t * 16;
    int loc[16];
    int tot = 0;
    #pragma unroll
    for (int i = 0; i < 16; i++) {
        int idx = base + i;
        int v = (idx < M) ? cnt[idx] : 0;
        loc[i] = tot; tot += v;
    }
    s[t] = tot; __syncthreads();
    for (int off = 1; off < 256; off <<= 1) {
        int v = (t >= off) ? s[t - off] : 0;
        __syncthreads();
        s[t] += v;
        __syncthreads();
    }
    int texc = s[t] - tot;           // exclusive prefix of this thread
    int bb = blkOff[b];
    #pragma unroll
    for (int i = 0; i < 16; i++) {
        int idx = base + i;
        if (idx < M) { int o = bb + texc + loc[i]; offs[idx] = o; curs[idx] = o; }
    }
}

__global__ __launch_bounds__(256) void scatter_kernel(
    const int* __restrict__ src, const int* __restrict__ dst, const int* __restrict__ et,
    int* __restrict__ cursors, int* __restrict__ esrc)
{
    int i = blockIdx.x * 256 + threadIdx.x;
    if (i < EE) {
        int pos = atomicAdd(&cursors[dst[i] * RR + et[i]], 1);
        esrc[pos] = src[i];
    }
}

// ---------------- fused aggregate + GEMM layer ----------------
// block = 256 threads, 32-node tile. For r in 0..nrel-1: stage bucket-mean of
// hin[src] into LDS A[32][IN]; r==nrel stages hin itself (root). Then
// acc[4][8] += A @ W_r register-tiled (thread = 4 nodes x 8 outs).
template<int IN, int ACT>
__global__ __launch_bounds__(256) void layer_kernel(
    const float* __restrict__ hin,
    const int* __restrict__ esrc,
    const int* __restrict__ offs,
    const int* __restrict__ cnts,
    const float* __restrict__ W,      // [nrel, IN, 256]
    const float* __restrict__ root,   // [IN, 256]
    const float* __restrict__ bias,   // [256]
    float* __restrict__ hout,         // [N, 256]
    int nrel)
{
    __shared__ float A[32][IN + 4];
    const int t = threadIdx.x;
    const int tx = t & 31;      // out group: outs tx*8 .. tx*8+7
    const int ty = t >> 5;      // node group: nodes ty*4 .. ty*4+3
    const int base = blockIdx.x * 32;
    const int an = t >> 3;      // aggregation node 0..31
    const int ac = t & 7;       // aggregation dim chunk 0..7
    const int node = base + an;

    float bv[8];
    #pragma unroll
    for (int o = 0; o < 8; o++) bv[o] = bias[tx * 8 + o];

    float acc[4][8];
    #pragma unroll
    for (int i = 0; i < 4; i++)
        #pragma unroll
        for (int o = 0; o < 8; o++) acc[i][o] = 0.f;

    for (int r = 0; r <= nrel; r++) {
        const bool isroot = (r == nrel);
        if (isroot) {
            if (node < NN) {
                #pragma unroll
                for (int jj = 0; jj < IN / 32; jj++) {
                    int j = jj * 32 + ac * 4;
                    *(float4*)&A[an][j] = *(const float4*)&hin[(size_t)node * IN + j];
                }
            } else {
                float4 z = make_float4(0.f, 0.f, 0.f, 0.f);
                #pragma unroll
                for (int jj = 0; jj < IN / 32; jj++) *(float4*)&A[an][jj * 32 + ac * 4] = z;
            }
        } else {
            float4 z = make_float4(0.f, 0.f, 0.f, 0.f);
            #pragma unroll
            for (int jj = 0; jj < IN / 32; jj++) *(float4*)&A[an][jj * 32 + ac * 4] = z;
            if (node < NN) {
                int bidx = node * RR + r;
                int st = offs[bidx];
                int cn = cnts[bidx];
                if (cn > 0) {
                    for (int e = 0; e < cn; e++) {
                        const float* hs = hin + (size_t)esrc[st + e] * IN;
                        #pragma unroll
                        for (int jj = 0; jj < IN / 32; jj++) {
                            int j = jj * 32 + ac * 4;
                            float4 v = *(const float4*)&hs[j];
                            float4 a = *(float4*)&A[an][j];
                            a.x += v.x; a.y += v.y; a.z += v.z; a.w += v.w;
                            *(float4*)&A[an][j] = a;
                        }
                    }
                    float nrm = 1.0f / (float)cn;   // mean aggregation (clip>=1 implicit: cn>0)
                    #pragma unroll
                    for (int jj = 0; jj < IN / 32; jj++) {
                        int j = jj * 32 + ac * 4;
                        float4 a = *(float4*)&A[an][j];
                        a.x *= nrm; a.y *= nrm; a.z *= nrm; a.w *= nrm;
                        *(float4*)&A[an][j] = a;
                    }
                }
            }
        }
        __syncthreads();

        const float* __restrict__ Wr = isroot ? root : (W + (size_t)r * IN * DL);
        for (int k = 0; k < IN; k += 4) {
            float4 av[4];
            #pragma unroll
            for (int i = 0; i < 4; i++) av[i] = *(const float4*)&A[ty * 4 + i][k];
            float4 wlo[4], whi[4];
            #pragma unroll
            for (int kk = 0; kk < 4; kk++) {
                const float* wp = Wr + (size_t)(k + kk) * DL + tx * 8;
                wlo[kk] = *(const float4*)&wp[0];
                whi[kk] = *(const float4*)&wp[4];
            }
            #pragma unroll
            for (int i = 0; i < 4; i++) {
                #pragma unroll
                for (int kk = 0; kk < 4; kk++) {
                    float aik = (kk == 0) ? av[i].x : ((kk == 1) ? av[i].y : ((kk == 2) ? av[i].z : av[i].w));
                    acc[i][0] += aik * wlo[kk].x;
                    acc[i][1] += aik * wlo[kk].y;
                    acc[i][2] += aik * wlo[kk].z;
                    acc[i][3] += aik * wlo[kk].w;
                    acc[i][4] += aik * whi[kk].x;
                    acc[i][5] += aik * whi[kk].y;
                    acc[i][6] += aik * whi[kk].z;
                    acc[i][7] += aik * whi[kk].w;
                }
            }
        }
        __syncthreads();
    }

    #pragma unroll
    for (int i = 0; i < 4; i++) {
        int n = base + ty * 4 + i;
        if (n < NN) {
            float v[8];
            #pragma unroll
            for (int o = 0; o < 8; o++) {
                float u = acc[i][o] + bv[o];
                v[o] = ACT ? sigmoidf_(u) : u;
            }
            float4 o0 = make_float4(v[0], v[1], v[2], v[3]);
            float4 o1 = make_float4(v[4], v[5], v[6], v[7]);
            *(float4*)&hout[(size_t)n * DL + tx * 8]     = o0;
            *(float4*)&hout[(size_t)n * DL + tx * 8 + 4] = o1;
        }
    }
}

// ---------------- BatchNorm stats over hg1 columns ----------------
__global__ __launch_bounds__(256) void bnstats_kernel(
    const float* __restrict__ hg1, float* __restrict__ colsum, float* __restrict__ colsum2)
{
    int col = threadIdx.x;            // 256 columns
    int row0 = blockIdx.x * 128;
    int rend = min(row0 + 128, NN);
    float s = 0.f, s2 = 0.f;
    for (int r = row0; r < rend; r++) {
        float v = hg1[(size_t)r * DL + col];
        s += v; s2 += v * v;
    }
    atomicAdd(&colsum[col], s);
    atomicAdd(&colsum2[col], s2);
}

__global__ void bnfinal_kernel(
    const float* __restrict__ colsum, const float* __restrict__ colsum2,
    const float* __restrict__ gamma, float* __restrict__ mu, float* __restrict__ aa)
{
    int c = threadIdx.x;
    if (c < DL) {
        float m = colsum[c] / (float)NN;
        float var = colsum2[c] / (float)NN - m * m;
        mu[c] = m;
        aa[c] = rsqrtf(var + 1e-5f) * gamma[c];
    }
}

// ---------------- gate = relu(BN(hg1)) @ Wg2 + bg2 ; segment max ----------------
__global__ __launch_bounds__(256) void gate_kernel(
    const float* __restrict__ hg1, const float* __restrict__ mu,
    const float* __restrict__ aa, const float* __restrict__ beta,
    const float* __restrict__ Wg2, const float* __restrict__ bg2,
    const int* __restrict__ batch,
    float* __restrict__ gate, unsigned* __restrict__ gmaxu)
{
    int lane = threadIdx.x & 63;
    int wid = (blockIdx.x * blockDim.x + threadIdx.x) >> 6;
    int nw = (gridDim.x * blockDim.x) >> 6;
    for (int n = wid; n < NN; n += nw) {
        float s = 0.f;
        #pragma unroll
        for (int c = 0; c < 4; c++) {
            int d = c * 64 + lane;
            float v = hg1[(size_t)n * DL + d];
            float xn = (v - mu[d]) * aa[d] + beta[d];
            xn = fmaxf(xn, 0.f);
            s += xn * Wg2[d];
        }
        #pragma unroll
        for (int o = 32; o > 0; o >>= 1) s += __shfl_down(s, o, 64);
        if (lane == 0) {
            float g = s + bg2[0];
            gate[n] = g;
            atomicMax(&gmaxu[batch[n]], fenc(g));
        }
    }
}

__global__ __launch_bounds__(256) void expdenom_kernel(
    const float* __restrict__ gate, const int* __restrict__ batch,
    const unsigned* __restrict__ gmaxu, float* __restrict__ ealpha, float* __restrict__ denom)
{
    int i = blockIdx.x * 256 + threadIdx.x;
    if (i < NN) {
        int b = batch[i];
        float ex = expf(gate[i] - fdec(gmaxu[b]));
        ealpha[i] = ex;
        atomicAdd(&denom[b], ex);
    }
}

__global__ __launch_bounds__(256) void alpha_kernel(
    float* __restrict__ ealpha, const float* __restrict__ denom, const int* __restrict__ batch)
{
    int i = blockIdx.x * 256 + threadIdx.x;
    if (i < NN) ealpha[i] = ealpha[i] / denom[batch[i]];
}

// ---------------- pooled[g] = sum alpha[n] * h2[n] (batch sorted) ----------------
__global__ __launch_bounds__(256) void pool_kernel(
    const float* __restrict__ h2, const float* __restrict__ alpha,
    const int* __restrict__ batch, float* __restrict__ pooled)
{
    int col = threadIdx.x;            // 256
    int row0 = blockIdx.x * 128;
    if (row0 >= NN) return;
    int rend = min(row0 + 128, NN);
    float accv = 0.f;
    int curg = batch[row0];
    for (int r = row0; r < rend; r++) {
        int g = batch[r];
        if (g != curg) {
            atomicAdd(&pooled[curg * DL + col], accv);
            accv = 0.f; curg = g;
        }
        accv += alpha[r] * h2[(size_t)r * DL + col];
    }
    atomicAdd(&pooled[curg * DL + col], accv);
}

__global__ void head_kernel(
    const float* __restrict__ pooled, const float* __restrict__ Wgl,
    const float* __restrict__ bgl, float* __restrict__ out)
{
    int g = blockIdx.x;
    int lane = threadIdx.x;           // 64
    float s = 0.f;
    #pragma unroll
    for (int c = 0; c < 4; c++) {
        int d = c * 64 + lane;
        s += pooled[g * DL + d] * Wgl[d];
    }
    #pragma unroll
    for (int o = 32; o > 0; o >>= 1) s += __shfl_down(s, o, 64);
    if (lane == 0) out[g] = sigmoidf_(s + bgl[0]);
}

extern "C" void kernel_launch(void* const* d_in, const int* in_sizes, int n_in,
                              void* d_out, int out_size, void* d_ws, size_t ws_size,
                              hipStream_t stream)
{
    const int* x      = (const int*)d_in[0];
    const int* ei     = (const int*)d_in[1];
    const int* etype  = (const int*)d_in[2];
    const int* batch  = (const int*)d_in[3];
    const float* e0   = (const float*)d_in[4];
    const float* e1   = (const float*)d_in[5];
    const float* e2   = (const float*)d_in[6];
    const float* e3   = (const float*)d_in[7];
    const float* e4   = (const float*)d_in[8];
    const float* e5   = (const float*)d_in[9];
    const float* W1   = (const float*)d_in[10];
    const float* root1= (const float*)d_in[11];
    const float* b1   = (const float*)d_in[12];
    const float* W2   = (const float*)d_in[13];
    const float* root2= (const float*)d_in[14];
    const float* b2   = (const float*)d_in[15];
    const float* Wg1  = (const float*)d_in[16];
    const float* bg1  = (const float*)d_in[17];
    const float* gamma= (const float*)d_in[18];
    const float* beta = (const float*)d_in[19];
    const float* Wg2  = (const float*)d_in[20];
    const float* bg2  = (const float*)d_in[21];
    const float* Wgl  = (const float*)d_in[22];
    const float* bgl  = (const float*)d_in[23];
    float* out = (float*)d_out;

    const int* esrc_in = ei;          // edge_index[0]
    const int* edst_in = ei + EE;     // edge_index[1]

    char* ws = (char*)d_ws;
    size_t off = 0;
    auto alloc = [&](size_t b) -> char* {
        char* p = ws + off;
        off += (b + 255) & ~(size_t)255;
        return p;
    };
    float* h0      = (float*)alloc((size_t)NN * D0 * 4);   // 76.8 MB (reused as hg1)
    float* h1      = (float*)alloc((size_t)NN * DL * 4);   // 51.2 MB
    float* h2      = (float*)alloc((size_t)NN * DL * 4);   // 51.2 MB
    size_t zstart = off;                                   // ---- zeroed region ----
    int*      counts  = (int*)alloc((size_t)NN * RR * 4);
    float*    colsum  = (float*)alloc(DL * 4);
    float*    colsum2 = (float*)alloc(DL * 4);
    unsigned* gmaxu   = (unsigned*)alloc(GG * 4);
    float*    denom   = (float*)alloc(GG * 4);
    float*    pooled  = (float*)alloc((size_t)GG * DL * 4);
    size_t zbytes = off - zstart;                          // ---- end zeroed ----
    int*   offs    = (int*)alloc((size_t)NN * RR * 4);
    int*   cursors = (int*)alloc((size_t)NN * RR * 4);
    int*   esrc    = (int*)alloc((size_t)EE * 4);
    int*   blkSums = (int*)alloc(512);
    int*   blkOff  = (int*)alloc(512);
    float* mu      = (float*)alloc(DL * 4);
    float* aa      = (float*)alloc(DL * 4);
    float* gate    = (float*)alloc((size_t)NN * 4);
    float* ealpha  = (float*)alloc((size_t)NN * 4);
    float* hg1 = h0;   // reuse: h0 dead after layer1

    if (ws_size < off) return;   // fail loudly (wrong output) rather than corrupt

    hipMemsetAsync(ws + zstart, 0, zbytes, stream);

    embed_kernel<<<(NN * 96 + 255) / 256, 256, 0, stream>>>(x, e0, e1, e2, e3, e4, e5, h0);
    count_kernel<<<(EE + 255) / 256, 256, 0, stream>>>(edst_in, etype, counts);

    const int M = NN * RR;
    const int NB = (M + SCAN_CHUNK - 1) / SCAN_CHUNK;   // 98
    scanA_kernel<<<NB, 256, 0, stream>>>(counts, M, blkSums);
    scanB_kernel<<<1, 64, 0, stream>>>(blkSums, NB, blkOff);
    scanC_kernel<<<NB, 256, 0, stream>>>(counts, M, blkOff, offs, cursors);
    scatter_kernel<<<(EE + 255) / 256, 256, 0, stream>>>(esrc_in, edst_in, etype, cursors, esrc);

    layer_kernel<D0, 1><<<(NN + 31) / 32, 256, 0, stream>>>(h0, esrc, offs, counts, W1, root1, b1, h1, RR);
    layer_kernel<DL, 1><<<(NN + 31) / 32, 256, 0, stream>>>(h1, esrc, offs, counts, W2, root2, b2, h2, RR);
    layer_kernel<DL, 0><<<(NN + 31) / 32, 256, 0, stream>>>(h2, esrc, offs, counts, nullptr, Wg1, bg1, hg1, 0);

    bnstats_kernel<<<(NN + 127) / 128, 256, 0, stream>>>(hg1, colsum, colsum2);
    bnfinal_kernel<<<1, 256, 0, stream>>>(colsum, colsum2, gamma, mu, aa);
    gate_kernel<<<512, 256, 0, stream>>>(hg1, mu, aa, beta, Wg2, bg2, batch, gate, gmaxu);
    expdenom_kernel<<<(NN + 255) / 256, 256, 0, stream>>>(gate, batch, gmaxu, ealpha, denom);
    alpha_kernel<<<(NN + 255) / 256, 256, 0, stream>>>(ealpha, denom, batch);
    pool_kernel<<<(NN + 127) / 128, 256, 0, stream>>>(h2, ealpha, batch, pooled);
    head_kernel<<<GG, 64, 0, stream>>>(pooled, Wgl, bgl, out);
}

// Round 2
// 2034.847 us; speedup vs baseline: 1.7297x; 1.7297x over previous
//
#include <hip/hip_runtime.h>
#include <hip/hip_bf16.h>
#include <cstdint>

#define NN 50000
#define EE 800000
#define RR 8
#define GG 128
#define D0 384
#define DL 256

typedef __attribute__((ext_vector_type(8))) short bf16x8;
typedef __attribute__((ext_vector_type(4))) float f32x4;

__device__ __forceinline__ float sigmoidf_(float x) { return 1.0f / (1.0f + expf(-x)); }

// fp32 -> bf16 (round to nearest even)
__device__ __forceinline__ ushort f2bf(float f) {
    uint u = __float_as_uint(f);
    u += 0x7fffu + ((u >> 16) & 1u);
    return (ushort)(u >> 16);
}

// order-preserving float->uint encoding for atomicMax
__device__ __forceinline__ unsigned fenc(float x) {
    unsigned u = __float_as_uint(x);
    return (u & 0x80000000u) ? ~u : (u | 0x80000000u);
}
__device__ __forceinline__ float fdec(unsigned u) {
    unsigned b = (u & 0x80000000u) ? (u & 0x7fffffffu) : ~u;
    return __uint_as_float(b);
}

// ---------------- embedding concat: h0[n, 0:384] ----------------
__global__ __launch_bounds__(256) void embed_kernel(
    const int* __restrict__ x,
    const float* __restrict__ e0, const float* __restrict__ e1,
    const float* __restrict__ e2, const float* __restrict__ e3,
    const float* __restrict__ e4, const float* __restrict__ e5,
    float* __restrict__ h0)
{
    int idx = blockIdx.x * 256 + threadIdx.x;   // over NN*96 float4s
    if (idx >= NN * 96) return;
    int n = idx / 96;
    int q = idx - n * 96;
    int d = q * 4;
    int tbl = d >> 6;
    int w = d & 63;
    int row = x[n * 6 + tbl];
    const float* src;
    switch (tbl) {
        case 0: src = e0; break; case 1: src = e1; break; case 2: src = e2; break;
        case 3: src = e3; break; case 4: src = e4; break; default: src = e5; break;
    }
    *(float4*)&h0[(size_t)n * D0 + d] = *(const float4*)&src[row * 64 + w];
}

// ---------------- weight convert + transpose: WbT[r][n][k] = bf16(W[r][k][n]) ----------------
__global__ __launch_bounds__(256) void cvtT_kernel(
    const float* __restrict__ W, const float* __restrict__ root,
    ushort* __restrict__ WbT, int nrel, int IN)
{
    int idx = blockIdx.x * 256 + threadIdx.x;
    int tot = (nrel + 1) * DL * IN;
    if (idx >= tot) return;
    int k = idx % IN;
    int rn = idx / IN;
    int n = rn % DL;
    int r = rn / DL;
    float v = (r < nrel) ? W[((size_t)r * IN + k) * DL + n] : root[(size_t)k * DL + n];
    WbT[idx] = f2bf(v);
}

// ---------------- CSR build ----------------
__global__ __launch_bounds__(256) void count_kernel(
    const int* __restrict__ dst, const int* __restrict__ et, int* __restrict__ counts)
{
    int i = blockIdx.x * 256 + threadIdx.x;
    if (i < EE) atomicAdd(&counts[dst[i] * RR + et[i]], 1);
}

#define SCAN_CHUNK 4096
__global__ __launch_bounds__(256) void scanA_kernel(const int* __restrict__ cnt, int M, int* __restrict__ blkSums)
{
    __shared__ int s[256];
    int b = blockIdx.x, t = threadIdx.x;
    int base = b * SCAN_CHUNK + t * 16;
    int tot = 0;
    #pragma unroll
    for (int i = 0; i < 16; i++) { int idx = base + i; if (idx < M) tot += cnt[idx]; }
    s[t] = tot; __syncthreads();
    for (int off = 128; off > 0; off >>= 1) {
        if (t < off) s[t] += s[t + off];
        __syncthreads();
    }
    if (t == 0) blkSums[b] = s[0];
}

__global__ void scanB_kernel(const int* __restrict__ blkSums, int NB, int* __restrict__ blkOff)
{
    if (threadIdx.x == 0) {
        int run = 0;
        for (int i = 0; i < NB; i++) { blkOff[i] = run; run += blkSums[i]; }
    }
}

__global__ __launch_bounds__(256) void scanC_kernel(
    const int* __restrict__ cnt, int M, const int* __restrict__ blkOff,
    int* __restrict__ offs, int* __restrict__ curs)
{
    __shared__ int s[256];
    int b = blockIdx.x, t = threadIdx.x;
    int base = b * SCAN_CHUNK + t * 16;
    int loc[16];
    int tot = 0;
    #pragma unroll
    for (int i = 0; i < 16; i++) {
        int idx = base + i;
        int v = (idx < M) ? cnt[idx] : 0;
        loc[i] = tot; tot += v;
    }
    s[t] = tot; __syncthreads();
    for (int off = 1; off < 256; off <<= 1) {
        int v = (t >= off) ? s[t - off] : 0;
        __syncthreads();
        s[t] += v;
        __syncthreads();
    }
    int texc = s[t] - tot;           // exclusive prefix of this thread
    int bb = blkOff[b];
    #pragma unroll
    for (int i = 0; i < 16; i++) {
        int idx = base + i;
        if (idx < M) { int o = bb + texc + loc[i]; offs[idx] = o; curs[idx] = o; }
    }
}

__global__ __launch_bounds__(256) void scatter_kernel(
    const int* __restrict__ src, const int* __restrict__ dst, const int* __restrict__ et,
    int* __restrict__ cursors, int* __restrict__ esrc)
{
    int i = blockIdx.x * 256 + threadIdx.x;
    if (i < EE) {
        int pos = atomicAdd(&cursors[dst[i] * RR + et[i]], 1);
        esrc[pos] = src[i];
    }
}

// ---------------- fused aggregate + bf16-MFMA GEMM layer ----------------
// block = 256 threads (4 waves), 32-node tile, 256 output cols.
// Per relation: register-aggregate bucket means -> bf16 LDS A[32][IN];
// each wave computes 32x64 output slice via v_mfma_f32_16x16x32_bf16.
template<int IN, int ACT>
__global__ __launch_bounds__(256) void layer_mfma(
    const float* __restrict__ hin,
    const int* __restrict__ esrc,
    const int* __restrict__ offs,
    const int* __restrict__ cnts,
    const ushort* __restrict__ WbT,   // [(nrel+1)][DL][IN] bf16, n-major
    const float* __restrict__ bias,   // [DL]
    float* __restrict__ hout,         // [N, DL]
    int nrel)
{
    constexpr int NC = IN / 32;       // float4 chunks per agg thread; also K-steps
    constexpr int LDA_ = IN + 8;      // pad 8 bf16 = 16B -> <=2-way bank aliasing
    __shared__ ushort Ab[32][LDA_];

    const int t    = threadIdx.x;
    const int an   = t >> 3;          // agg node 0..31
    const int ac   = t & 7;           // agg chunk 0..7
    const int base = blockIdx.x * 32;
    const int node = base + an;
    const int lane = t & 63;
    const int wv   = t >> 6;          // wave 0..3
    const int l15  = lane & 15;
    const int kg   = lane >> 4;       // k-group 0..3
    const int wcol = wv * 64;

    f32x4 acc[2][4];
    #pragma unroll
    for (int mt = 0; mt < 2; mt++)
        #pragma unroll
        for (int nt = 0; nt < 4; nt++) acc[mt][nt] = (f32x4){0.f, 0.f, 0.f, 0.f};

    // B fragment base pointers (per n-tile), relation offset added in loop
    const ushort* bp[4];
    #pragma unroll
    for (int nt = 0; nt < 4; nt++)
        bp[nt] = WbT + (size_t)(wcol + nt * 16 + l15) * IN + kg * 4;

    union FR { bf16x8 v; uint u[4]; };

    for (int r = 0; r <= nrel; r++) {
        // ---- aggregation into registers ----
        float4 s[NC];
        #pragma unroll
        for (int j = 0; j < NC; j++) s[j] = make_float4(0.f, 0.f, 0.f, 0.f);
        if (node < NN) {
            if (r == nrel) {               // root: node's own features
                const float* hp = hin + (size_t)node * IN;
                #pragma unroll
                for (int j = 0; j < NC; j++) s[j] = *(const float4*)&hp[j * 32 + ac * 4];
            } else {
                int bidx = node * RR + r;
                int st = offs[bidx], cn = cnts[bidx];
                for (int e = 0; e < cn; e++) {
                    const float* hp = hin + (size_t)esrc[st + e] * IN;
                    #pragma unroll
                    for (int j = 0; j < NC; j++) {
                        float4 v = *(const float4*)&hp[j * 32 + ac * 4];
                        s[j].x += v.x; s[j].y += v.y; s[j].z += v.z; s[j].w += v.w;
                    }
                }
                if (cn > 1) {
                    float nrm = 1.0f / (float)cn;   // mean aggregation
                    #pragma unroll
                    for (int j = 0; j < NC; j++) {
                        s[j].x *= nrm; s[j].y *= nrm; s[j].z *= nrm; s[j].w *= nrm;
                    }
                }
            }
        }
        #pragma unroll
        for (int j = 0; j < NC; j++) {
            ushort4 pk;
            pk.x = f2bf(s[j].x); pk.y = f2bf(s[j].y);
            pk.z = f2bf(s[j].z); pk.w = f2bf(s[j].w);
            *(ushort4*)&Ab[an][j * 32 + ac * 4] = pk;
        }
        __syncthreads();

        // ---- MFMA over K = IN ----
        const size_t roff = (size_t)r * DL * IN;
        for (int ks = 0; ks < NC; ks++) {
            FR a0, a1, bb[4];
            const ushort* ap0 = &Ab[l15][ks * 32 + kg * 4];
            const ushort* ap1 = &Ab[16 + l15][ks * 32 + kg * 4];
            uint2 x0 = *(const uint2*)ap0;
            uint2 x1 = *(const uint2*)(ap0 + 16);
            a0.u[0] = x0.x; a0.u[1] = x0.y; a0.u[2] = x1.x; a0.u[3] = x1.y;
            uint2 y0 = *(const uint2*)ap1;
            uint2 y1 = *(const uint2*)(ap1 + 16);
            a1.u[0] = y0.x; a1.u[1] = y0.y; a1.u[2] = y1.x; a1.u[3] = y1.y;
            #pragma unroll
            for (int nt = 0; nt < 4; nt++) {
                const ushort* p = bp[nt] + roff + ks * 32;
                uint2 lo = *(const uint2*)p;
                uint2 hi = *(const uint2*)(p + 16);
                bb[nt].u[0] = lo.x; bb[nt].u[1] = lo.y; bb[nt].u[2] = hi.x; bb[nt].u[3] = hi.y;
            }
            #pragma unroll
            for (int nt = 0; nt < 4; nt++) {
                acc[0][nt] = __builtin_amdgcn_mfma_f32_16x16x32_bf16(a0.v, bb[nt].v, acc[0][nt], 0, 0, 0);
                acc[1][nt] = __builtin_amdgcn_mfma_f32_16x16x32_bf16(a1.v, bb[nt].v, acc[1][nt], 0, 0, 0);
            }
        }
        __syncthreads();
    }

    // ---- epilogue: bias + activation, C/D layout col=lane&15, row=(lane>>4)*4+i ----
    #pragma unroll
    for (int nt = 0; nt < 4; nt++) {
        int col = wcol + nt * 16 + l15;
        float bv = bias[col];
        #pragma unroll
        for (int mt = 0; mt < 2; mt++) {
            #pragma unroll
            for (int i = 0; i < 4; i++) {
                int n = base + mt * 16 + kg * 4 + i;
                if (n < NN) {
                    float v = acc[mt][nt][i] + bv;
                    hout[(size_t)n * DL + col] = ACT ? sigmoidf_(v) : v;
                }
            }
        }
    }
}

// ---------------- BatchNorm stats over hg1 columns ----------------
__global__ __launch_bounds__(256) void bnstats_kernel(
    const float* __restrict__ hg1, float* __restrict__ colsum, float* __restrict__ colsum2)
{
    int col = threadIdx.x;            // 256 columns
    int row0 = blockIdx.x * 128;
    int rend = min(row0 + 128, NN);
    float s = 0.f, s2 = 0.f;
    for (int r = row0; r < rend; r++) {
        float v = hg1[(size_t)r * DL + col];
        s += v; s2 += v * v;
    }
    atomicAdd(&colsum[col], s);
    atomicAdd(&colsum2[col], s2);
}

__global__ void bnfinal_kernel(
    const float* __restrict__ colsum, const float* __restrict__ colsum2,
    const float* __restrict__ gamma, float* __restrict__ mu, float* __restrict__ aa)
{
    int c = threadIdx.x;
    if (c < DL) {
        float m = colsum[c] / (float)NN;
        float var = colsum2[c] / (float)NN - m * m;
        mu[c] = m;
        aa[c] = rsqrtf(var + 1e-5f) * gamma[c];
    }
}

// ---------------- gate = relu(BN(hg1)) @ Wg2 + bg2 ; segment max ----------------
__global__ __launch_bounds__(256) void gate_kernel(
    const float* __restrict__ hg1, const float* __restrict__ mu,
    const float* __restrict__ aa, const float* __restrict__ beta,
    const float* __restrict__ Wg2, const float* __restrict__ bg2,
    const int* __restrict__ batch,
    float* __restrict__ gate, unsigned* __restrict__ gmaxu)
{
    int lane = threadIdx.x & 63;
    int wid = (blockIdx.x * blockDim.x + threadIdx.x) >> 6;
    int nw = (gridDim.x * blockDim.x) >> 6;
    for (int n = wid; n < NN; n += nw) {
        float s = 0.f;
        #pragma unroll
        for (int c = 0; c < 4; c++) {
            int d = c * 64 + lane;
            float v = hg1[(size_t)n * DL + d];
            float xn = (v - mu[d]) * aa[d] + beta[d];
            xn = fmaxf(xn, 0.f);
            s += xn * Wg2[d];
        }
        #pragma unroll
        for (int o = 32; o > 0; o >>= 1) s += __shfl_down(s, o, 64);
        if (lane == 0) {
            float g = s + bg2[0];
            gate[n] = g;
            atomicMax(&gmaxu[batch[n]], fenc(g));
        }
    }
}

__global__ __launch_bounds__(256) void expdenom_kernel(
    const float* __restrict__ gate, const int* __restrict__ batch,
    const unsigned* __restrict__ gmaxu, float* __restrict__ ealpha, float* __restrict__ denom)
{
    int i = blockIdx.x * 256 + threadIdx.x;
    if (i < NN) {
        int b = batch[i];
        float ex = expf(gate[i] - fdec(gmaxu[b]));
        ealpha[i] = ex;
        atomicAdd(&denom[b], ex);
    }
}

__global__ __launch_bounds__(256) void alpha_kernel(
    float* __restrict__ ealpha, const float* __restrict__ denom, const int* __restrict__ batch)
{
    int i = blockIdx.x * 256 + threadIdx.x;
    if (i < NN) ealpha[i] = ealpha[i] / denom[batch[i]];
}

// ---------------- pooled[g] = sum alpha[n] * h2[n] (batch sorted) ----------------
__global__ __launch_bounds__(256) void pool_kernel(
    const float* __restrict__ h2, const float* __restrict__ alpha,
    const int* __restrict__ batch, float* __restrict__ pooled)
{
    int col = threadIdx.x;            // 256
    int row0 = blockIdx.x * 128;
    if (row0 >= NN) return;
    int rend = min(row0 + 128, NN);
    float accv = 0.f;
    int curg = batch[row0];
    for (int r = row0; r < rend; r++) {
        int g = batch[r];
        if (g != curg) {
            atomicAdd(&pooled[curg * DL + col], accv);
            accv = 0.f; curg = g;
        }
        accv += alpha[r] * h2[(size_t)r * DL + col];
    }
    atomicAdd(&pooled[curg * DL + col], accv);
}

__global__ void head_kernel(
    const float* __restrict__ pooled, const float* __restrict__ Wgl,
    const float* __restrict__ bgl, float* __restrict__ out)
{
    int g = blockIdx.x;
    int lane = threadIdx.x;           // 64
    float s = 0.f;
    #pragma unroll
    for (int c = 0; c < 4; c++) {
        int d = c * 64 + lane;
        s += pooled[g * DL + d] * Wgl[d];
    }
    #pragma unroll
    for (int o = 32; o > 0; o >>= 1) s += __shfl_down(s, o, 64);
    if (lane == 0) out[g] = sigmoidf_(s + bgl[0]);
}

extern "C" void kernel_launch(void* const* d_in, const int* in_sizes, int n_in,
                              void* d_out, int out_size, void* d_ws, size_t ws_size,
                              hipStream_t stream)
{
    const int* x      = (const int*)d_in[0];
    const int* ei     = (const int*)d_in[1];
    const int* etype  = (const int*)d_in[2];
    const int* batch  = (const int*)d_in[3];
    const float* e0   = (const float*)d_in[4];
    const float* e1   = (const float*)d_in[5];
    const float* e2   = (const float*)d_in[6];
    const float* e3   = (const float*)d_in[7];
    const float* e4   = (const float*)d_in[8];
    const float* e5   = (const float*)d_in[9];
    const float* W1   = (const float*)d_in[10];
    const float* root1= (const float*)d_in[11];
    const float* b1   = (const float*)d_in[12];
    const float* W2   = (const float*)d_in[13];
    const float* root2= (const float*)d_in[14];
    const float* b2   = (const float*)d_in[15];
    const float* Wg1  = (const float*)d_in[16];
    const float* bg1  = (const float*)d_in[17];
    const float* gamma= (const float*)d_in[18];
    const float* beta = (const float*)d_in[19];
    const float* Wg2  = (const float*)d_in[20];
    const float* bg2  = (const float*)d_in[21];
    const float* Wgl  = (const float*)d_in[22];
    const float* bgl  = (const float*)d_in[23];
    float* out = (float*)d_out;

    const int* esrc_in = ei;          // edge_index[0]
    const int* edst_in = ei + EE;     // edge_index[1]

    char* ws = (char*)d_ws;
    size_t off = 0;
    auto alloc = [&](size_t b) -> char* {
        char* p = ws + off;
        off += (b + 255) & ~(size_t)255;
        return p;
    };
    float* h0      = (float*)alloc((size_t)NN * D0 * 4);   // 76.8 MB (reused as hg1)
    float* h1      = (float*)alloc((size_t)NN * DL * 4);   // 51.2 MB
    float* h2      = (float*)alloc((size_t)NN * DL * 4);   // 51.2 MB
    size_t zstart = off;                                   // ---- zeroed region ----
    int*      counts  = (int*)alloc((size_t)NN * RR * 4);
    float*    colsum  = (float*)alloc(DL * 4);
    float*    colsum2 = (float*)alloc(DL * 4);
    unsigned* gmaxu   = (unsigned*)alloc(GG * 4);
    float*    denom   = (float*)alloc(GG * 4);
    float*    pooled  = (float*)alloc((size_t)GG * DL * 4);
    size_t zbytes = off - zstart;                          // ---- end zeroed ----
    int*   offs    = (int*)alloc((size_t)NN * RR * 4);
    int*   cursors = (int*)alloc((size_t)NN * RR * 4);
    int*   esrc    = (int*)alloc((size_t)EE * 4);
    int*   blkSums = (int*)alloc(512);
    int*   blkOff  = (int*)alloc(512);
    float* mu      = (float*)alloc(DL * 4);
    float* aa      = (float*)alloc(DL * 4);
    float* gate    = (float*)alloc((size_t)NN * 4);
    float* ealpha  = (float*)alloc((size_t)NN * 4);
    ushort* WbT1   = (ushort*)alloc((size_t)9 * DL * D0 * 2);  // 1.77 MB
    ushort* WbT2   = (ushort*)alloc((size_t)9 * DL * DL * 2);  // 1.18 MB
    ushort* WbTg   = (ushort*)alloc((size_t)1 * DL * DL * 2);  // 131 KB
    float* hg1 = h0;   // reuse: h0 dead after layer1

    if (ws_size < off) return;   // fail loudly (wrong output) rather than corrupt

    hipMemsetAsync(ws + zstart, 0, zbytes, stream);

    embed_kernel<<<(NN * 96 + 255) / 256, 256, 0, stream>>>(x, e0, e1, e2, e3, e4, e5, h0);
    count_kernel<<<(EE + 255) / 256, 256, 0, stream>>>(edst_in, etype, counts);

    // weight bf16 transposes
    {
        int tot1 = 9 * DL * D0;
        cvtT_kernel<<<(tot1 + 255) / 256, 256, 0, stream>>>(W1, root1, WbT1, RR, D0);
        int tot2 = 9 * DL * DL;
        cvtT_kernel<<<(tot2 + 255) / 256, 256, 0, stream>>>(W2, root2, WbT2, RR, DL);
        int totg = 1 * DL * DL;
        cvtT_kernel<<<(totg + 255) / 256, 256, 0, stream>>>(nullptr, Wg1, WbTg, 0, DL);
    }

    const int M = NN * RR;
    const int NB = (M + SCAN_CHUNK - 1) / SCAN_CHUNK;   // 98
    scanA_kernel<<<NB, 256, 0, stream>>>(counts, M, blkSums);
    scanB_kernel<<<1, 64, 0, stream>>>(blkSums, NB, blkOff);
    scanC_kernel<<<NB, 256, 0, stream>>>(counts, M, blkOff, offs, cursors);
    scatter_kernel<<<(EE + 255) / 256, 256, 0, stream>>>(esrc_in, edst_in, etype, cursors, esrc);

    const int NBLK = (NN + 31) / 32;
    layer_mfma<D0, 1><<<NBLK, 256, 0, stream>>>(h0, esrc, offs, counts, WbT1, b1, h1, RR);
    layer_mfma<DL, 1><<<NBLK, 256, 0, stream>>>(h1, esrc, offs, counts, WbT2, b2, h2, RR);
    layer_mfma<DL, 0><<<NBLK, 256, 0, stream>>>(h2, esrc, offs, counts, WbTg, bg1, hg1, 0);

    bnstats_kernel<<<(NN + 127) / 128, 256, 0, stream>>>(hg1, colsum, colsum2);
    bnfinal_kernel<<<1, 256, 0, stream>>>(colsum, colsum2, gamma, mu, aa);
    gate_kernel<<<512, 256, 0, stream>>>(hg1, mu, aa, beta, Wg2, bg2, batch, gate, gmaxu);
    expdenom_kernel<<<(NN + 255) / 256, 256, 0, stream>>>(gate, batch, gmaxu, ealpha, denom);
    alpha_kernel<<<(NN + 255) / 256, 256, 0, stream>>>(ealpha, denom, batch);
    pool_kernel<<<(NN + 127) / 128, 256, 0, stream>>>(h2, ealpha, batch, pooled);
    head_kernel<<<GG, 64, 0, stream>>>(pooled, Wgl, bgl, out);
}